// Round 5
// baseline (108.587 us; speedup 1.0000x reference)
//
#include <hip/hip_runtime.h>
#include <hip/hip_bf16.h>
#include <stdint.h>

typedef short bf16x8 __attribute__((ext_vector_type(8)));
typedef float f32x4 __attribute__((ext_vector_type(4)));

#define DEVI static __device__ __forceinline__

constexpr int B_   = 32768;
constexpr int IN_  = 128;
constexpr int LF_  = 512;
constexpr int OUT_ = 32;

// ---- workspace layout (bytes) ----
// B-side matrices in MFMA-fragment order: chunk(tile,ks) at base + chunk*1KB,
// lane ln reads +ln*16B (fully coalesced). Fragment: row n = tile*16+(ln&15),
// k = ks*32 + (ln>>4)*8 .. +7.
constexpr size_t OFF_LTF = 0;                    // 32 x 16 x 1KB = 524,288
constexpr size_t OFF_W1F = 524288;               // 32 x 4  x 1KB = 131,072
constexpr size_t OFF_W2F = OFF_W1F + 131072;     // 3  x 16 x 1KB = 49,152

DEVI short f2bs(float f) { __hip_bfloat16 h = __float2bfloat16(f); return *(short*)&h; }

// fast tanh: 1 - 2/(e^{2v}+1)
DEVI float tanh_fast(float v) {
    float e = __expf(2.0f * v);
    return 1.0f - 2.0f * __builtin_amdgcn_rcpf(e + 1.0f);
}

DEVI bf16x8 fragGL(const __hip_bfloat16* base, int chunk, int ln) {
    return *(const bf16x8*)(base + ((size_t)chunk * 64 + ln) * 8);
}

// phi LDS tile: 64 rows x 64 chunks(16B); slot = row*64 + ((k>>3) ^ (row&7))
DEVI bf16x8 phiFrag(const char* p, int row, int kofs) {
    int c = (kofs >> 3) ^ (row & 7);
    return *(const bf16x8*)(p + (size_t)((row << 6) + c) * 16);
}
// x LDS tile: 64 rows x 16 chunks; slot = row*16 + ((k>>3) ^ (row&15))
DEVI bf16x8 xFrag(const char* p, int row, int kofs) {
    int c = (kofs >> 3) ^ (row & 15);
    return *(const bf16x8*)(p + (size_t)((row << 4) + c) * 16);
}

// ---------------- prep: build fragment-order W1F / W2F / LTF ----------------
__global__ __launch_bounds__(256) void k_prep(
        const float* __restrict__ w1, const float* __restrict__ w2,
        const float* __restrict__ lv, const float* __restrict__ qb,
        __hip_bfloat16* __restrict__ w1f, __hip_bfloat16* __restrict__ w2f,
        __hip_bfloat16* __restrict__ ltf) {
    int cid = blockIdx.x * 256 + threadIdx.x;
    if (cid < 8192) {                       // W1F: nt(32) x ks(4) x ln(64)
        int ln = cid & 63, ks = (cid >> 6) & 3, nt = cid >> 8;
        int n = nt * 16 + (ln & 15), kb = ks * 32 + (ln >> 4) * 8;
        const float* src = w1 + (size_t)n * IN_ + kb;
        bf16x8 o;
#pragma unroll
        for (int i = 0; i < 8; ++i) o[i] = f2bs(src[i]);
        *(bf16x8*)(w1f + (size_t)cid * 8) = o;
    } else if (cid < 11264) {               // W2F: nt(3) x ks(16) x ln(64)
        int c2 = cid - 8192;
        int ln = c2 & 63, ks = (c2 >> 6) & 15, nt = c2 >> 10;
        int n = nt * 16 + (ln & 15), kb = ks * 32 + (ln >> 4) * 8;
        bf16x8 o;
#pragma unroll
        for (int i = 0; i < 8; ++i) {
            float v = (n < OUT_) ? w2[(size_t)n * LF_ + kb + i]
                                 : (n == OUT_ ? qb[kb + i] : 0.f);
            o[i] = f2bs(v);
        }
        *(bf16x8*)(w2f + (size_t)c2 * 8) = o;
    } else if (cid < 44032) {               // LTF: t(32) x ks(16) x ln(64)
        int c3 = cid - 11264;
        int ln = c3 & 63, ks = (c3 >> 6) & 15, t = c3 >> 10;
        int j = t * 16 + (ln & 15), kb = ks * 32 + (ln >> 4) * 8;
        bf16x8 o;
#pragma unroll
        for (int i = 0; i < 8; ++i) {
            int k = kb + i;                 // Lt[j][k] = L[k][j], zero for k<j
            o[i] = (k >= j) ? f2bs(lv[(size_t)k * (k + 1) / 2 + j]) : (short)0;
        }
        *(bf16x8*)(ltf + (size_t)c3 * 8) = o;
    }
}

// ---------------- fused: x->phi(LDS)->pi,vf ----------------
// 512 threads (8 waves), M=64. LDS: phi 64KB | stage 16KB (x, then vfb/vfp)
// = 80KB -> 2 blocks/CU = 16 waves/CU = 4 waves/SIMD (VGPR must stay <=128).
__global__ __launch_bounds__(512, 4) void k_fused(
        const float* __restrict__ x, const __hip_bfloat16* __restrict__ w1f,
        const float* __restrict__ b1, const __hip_bfloat16* __restrict__ w2f,
        const __hip_bfloat16* __restrict__ ltf, const float* __restrict__ qcp,
        float* __restrict__ pi, float* __restrict__ vf) {
    __shared__ char smem[81920];
    char*  phiB  = smem;
    char*  stage = smem + 65536;
    float* vfb   = (float*)stage;          // 64 f32 (alias; valid after phase-1 barrier)
    float* vfp   = (float*)(stage + 256);  // 8x64 f32

    const int tid = threadIdx.x, wv = tid >> 6, ln = tid & 63;
    const int cl = ln & 15, q = ln >> 4;
    const int m0 = blockIdx.x * 64;

    // ---- phase 0: load+cast x tile (64x128 fp32 -> bf16) into LDS ----
#pragma unroll
    for (int it = 0; it < 2; ++it) {
        int slot = it * 512 + tid, row = slot >> 4, cg = slot & 15;
        const float4* p = (const float4*)(x + (size_t)(m0 + row) * IN_ + cg * 8);
        float4 u0 = p[0], u1 = p[1];
        bf16x8 pk;
        pk[0] = f2bs(u0.x); pk[1] = f2bs(u0.y); pk[2] = f2bs(u0.z); pk[3] = f2bs(u0.w);
        pk[4] = f2bs(u1.x); pk[5] = f2bs(u1.y); pk[6] = f2bs(u1.z); pk[7] = f2bs(u1.w);
        *(bf16x8*)(stage + (size_t)((row << 4) + (cg ^ (row & 15))) * 16) = pk;
    }
    __syncthreads();

    // ---- phase 1: phi^T tiles = W1tile(A) x x^T(B); packed b64 stores ----
    // acc[ni][mi]: D rows (q*4+r) = phi cols, D cols (cl) = batch rows.
    {
        f32x4 acc[4][4] = {};
        bf16x8 wfr[4], wnx[4];
#pragma unroll
        for (int ni = 0; ni < 4; ++ni) wfr[ni] = fragGL(w1f, (4 * wv + ni) * 4, ln);
#pragma unroll
        for (int ks = 0; ks < 4; ++ks) {
            bf16x8 a[4];
#pragma unroll
            for (int mi = 0; mi < 4; ++mi) a[mi] = xFrag(stage, mi * 16 + cl, ks * 32 + q * 8);
            if (ks < 3)
#pragma unroll
                for (int ni = 0; ni < 4; ++ni)
                    wnx[ni] = fragGL(w1f, (4 * wv + ni) * 4 + ks + 1, ln);
#pragma unroll
            for (int ni = 0; ni < 4; ++ni)
#pragma unroll
                for (int mi = 0; mi < 4; ++mi)
                    acc[ni][mi] = __builtin_amdgcn_mfma_f32_16x16x32_bf16(
                        wfr[ni], a[mi], acc[ni][mi], 0, 0, 0);
#pragma unroll
            for (int ni = 0; ni < 4; ++ni) wfr[ni] = wnx[ni];
        }
        // epilogue: tanh + bias, pack 4 consecutive phi-cols -> one ds_write_b64
#pragma unroll
        for (int ni = 0; ni < 4; ++ni) {
            float4 bb = *(const float4*)(b1 + wv * 64 + ni * 16 + q * 4);
            int c0 = wv * 8 + ni * 2 + (q >> 1);     // 16B chunk of col0
#pragma unroll
            for (int mi = 0; mi < 4; ++mi) {
                int row = mi * 16 + cl;
                short4 pk;
                pk.x = f2bs(tanh_fast(acc[ni][mi][0] + bb.x));
                pk.y = f2bs(tanh_fast(acc[ni][mi][1] + bb.y));
                pk.z = f2bs(tanh_fast(acc[ni][mi][2] + bb.z));
                pk.w = f2bs(tanh_fast(acc[ni][mi][3] + bb.w));
                *(short4*)(phiB + (size_t)((row << 6) + (c0 ^ (row & 7))) * 16
                           + (q & 1) * 8) = pk;
            }
        }
    }
    __syncthreads();   // phi complete; x/stage dead -> vfb/vfp alias valid

    // ---- phase 2: pi = phi @ W2ext^T; 12 (m,n) wave-tiles over 8 waves ----
    {
        int ids[2] = { (wv < 4) ? 2 * wv : 8 + (wv - 4), (wv < 4) ? 2 * wv + 1 : -1 };
#pragma unroll
        for (int u = 0; u < 2; ++u) {
            int id = ids[u];
            if (id < 0) continue;
            int mi = id & 3, ni = id >> 2;
            f32x4 a2 = {};
#pragma unroll
            for (int ks = 0; ks < 16; ++ks) {
                bf16x8 a = phiFrag(phiB, mi * 16 + cl, ks * 32 + q * 8);
                bf16x8 b = fragGL(w2f, ni * 16 + ks, ln);
                a2 = __builtin_amdgcn_mfma_f32_16x16x32_bf16(a, b, a2, 0, 0, 0);
            }
#pragma unroll
            for (int r = 0; r < 4; ++r) {
                int row = mi * 16 + q * 4 + r, col = ni * 16 + cl;
                if (col < OUT_)       pi[(size_t)(m0 + row) * OUT_ + col] = a2[r];
                else if (col == OUT_) vfb[row] = a2[r];   // phi.qb
            }
        }
    }

    // ---- phase 3: y = rowsum((phi @ L)^2); software-pipelined B loads ----
    {
        const int tl[4] = { wv, 15 - wv, 16 + wv, 31 - wv };
        int kstart[4];
#pragma unroll
        for (int j = 0; j < 4; ++j) kstart[j] = (tl[j] * 16) & ~31;  // exact: Lt 0-padded
        const int kmin = kstart[0];
        f32x4 acc[4][4] = {};   // [tile][mi]
        bf16x8 b[4];
#pragma unroll
        for (int j = 0; j < 4; ++j)
            if (kmin >= kstart[j]) b[j] = fragGL(ltf, tl[j] * 16 + (kmin >> 5), ln);
        for (int k0 = kmin; k0 < LF_; k0 += 32) {
            int k1 = k0 + 32;
            bf16x8 a[4];
#pragma unroll
            for (int mi = 0; mi < 4; ++mi) a[mi] = phiFrag(phiB, mi * 16 + cl, k0 + q * 8);
            bf16x8 bn[4];
            if (k1 < LF_) {
                int ks1 = k1 >> 5;
#pragma unroll
                for (int j = 0; j < 4; ++j)
                    if (k1 >= kstart[j]) bn[j] = fragGL(ltf, tl[j] * 16 + ks1, ln);
            }
#pragma unroll
            for (int j = 0; j < 4; ++j) {
                if (k0 >= kstart[j]) {          // wave-uniform
#pragma unroll
                    for (int mi = 0; mi < 4; ++mi)
                        acc[j][mi] = __builtin_amdgcn_mfma_f32_16x16x32_bf16(
                            a[mi], b[j], acc[j][mi], 0, 0, 0);
                }
            }
#pragma unroll
            for (int j = 0; j < 4; ++j) b[j] = bn[j];
        }
        // epilogue: sum u^2 over this wave's 64 cols, butterfly over col-lanes
#pragma unroll
        for (int mi = 0; mi < 4; ++mi)
#pragma unroll
            for (int r = 0; r < 4; ++r) {
                float s = 0.f;
#pragma unroll
                for (int j = 0; j < 4; ++j) { float t = acc[j][mi][r]; s += t * t; }
                s += __shfl_xor(s, 1, 64);
                s += __shfl_xor(s, 2, 64);
                s += __shfl_xor(s, 4, 64);
                s += __shfl_xor(s, 8, 64);
                if (cl == 0) vfp[wv * 64 + mi * 16 + q * 4 + r] = s;
            }
    }
    __syncthreads();
    if (tid < 64) {
        float v = vfb[tid] + qcp[0];
#pragma unroll
        for (int w = 0; w < 8; ++w) v += vfp[w * 64 + tid];
        vf[m0 + tid] = v;
    }
}

extern "C" void kernel_launch(void* const* d_in, const int* in_sizes, int n_in,
                              void* d_out, int out_size, void* d_ws, size_t ws_size,
                              hipStream_t stream) {
    const float* x  = (const float*)d_in[0];
    const float* w1 = (const float*)d_in[1];
    const float* b1 = (const float*)d_in[2];
    const float* w2 = (const float*)d_in[3];
    const float* lv = (const float*)d_in[4];
    const float* qb = (const float*)d_in[5];
    const float* qc = (const float*)d_in[6];

    char* ws = (char*)d_ws;
    __hip_bfloat16* ltf = (__hip_bfloat16*)(ws + OFF_LTF);
    __hip_bfloat16* w1f = (__hip_bfloat16*)(ws + OFF_W1F);
    __hip_bfloat16* w2f = (__hip_bfloat16*)(ws + OFF_W2F);

    float* pi = (float*)d_out;
    float* vf = pi + (size_t)B_ * OUT_;

    k_prep <<<172, 256, 0, stream>>>(w1, w2, lv, qb, w1f, w2f, ltf);
    k_fused<<<B_ / 64, 512, 0, stream>>>(x, w1f, b1, w2f, ltf, qc, pi, vf);
}